// Round 6
// baseline (414.810 us; speedup 1.0000x reference)
//
#include <hip/hip_runtime.h>

#define N_NODES 20000
#define N_EDGES 640000
#define D 128
#define TM 64   // GEMM tile rows per block

// ---------------- CSR build ----------------

__global__ void zero_counts_kernel(int* counts) {
    int i = blockIdx.x * blockDim.x + threadIdx.x;
    if (i < N_NODES) counts[i] = 0;
}

__global__ void count_deg_kernel(const int4* __restrict__ dst4, int* __restrict__ counts) {
    int e4 = blockIdx.x * blockDim.x + threadIdx.x;
    if (e4 < N_EDGES / 4) {
        int4 d = dst4[e4];
        atomicAdd(&counts[d.x], 1);
        atomicAdd(&counts[d.y], 1);
        atomicAdd(&counts[d.z], 1);
        atomicAdd(&counts[d.w], 1);
    }
}

__global__ __launch_bounds__(1024) void scan_offsets_kernel(const int* __restrict__ counts,
                                                            int* __restrict__ offsets,
                                                            int* __restrict__ cursor) {
    __shared__ int partial[1024];
    int t = threadIdx.x;
    const int CH = (N_NODES + 1023) / 1024;  // 20 nodes per thread
    int lo = t * CH;
    int hi = lo + CH; if (hi > N_NODES) hi = N_NODES;
    int s = 0;
    for (int i = lo; i < hi; ++i) s += counts[i];
    partial[t] = s;
    __syncthreads();
    for (int off = 1; off < 1024; off <<= 1) {
        int v = (t >= off) ? partial[t - off] : 0;
        __syncthreads();
        partial[t] += v;
        __syncthreads();
    }
    int run = (t == 0) ? 0 : partial[t - 1];
    for (int i = lo; i < hi; ++i) {
        int c = counts[i];
        offsets[i] = run;
        cursor[i]  = run;
        run += c;
    }
    if (t == 1023) offsets[N_NODES] = run;
}

__global__ void scatter_edges_kernel(const int4* __restrict__ src4, const int4* __restrict__ dst4,
                                     int* __restrict__ cursor, int* __restrict__ srcsort) {
    int e4 = blockIdx.x * blockDim.x + threadIdx.x;
    if (e4 < N_EDGES / 4) {
        int4 s = src4[e4];
        int4 d = dst4[e4];
        srcsort[atomicAdd(&cursor[d.x], 1)] = s.x;
        srcsort[atomicAdd(&cursor[d.y], 1)] = s.y;
        srcsort[atomicAdd(&cursor[d.z], 1)] = s.z;
        srcsort[atomicAdd(&cursor[d.w], 1)] = s.w;
    }
}

// ---------------- degree chain: u_{k+1} = (I+A) u_k ----------------

__global__ void deg_init_kernel(const int* __restrict__ counts, float* __restrict__ u2) {
    int i = blockIdx.x * blockDim.x + threadIdx.x;
    if (i < N_NODES) u2[i] = 1.0f + (float)counts[i];   // (I+A)·1
}

__global__ void deg_spmv_kernel(const int* __restrict__ offsets, const int* __restrict__ srcsort,
                                const float* __restrict__ uin, float* __restrict__ uout) {
    int i = blockIdx.x * blockDim.x + threadIdx.x;
    if (i < N_NODES) {
        float s = uin[i];
        int hi = offsets[i + 1];
        for (int k = offsets[i]; k < hi; ++k) s += uin[srcsort[k]];
        uout[i] = s;
    }
}

// ---------------- bias chain vectors: vv = [v1; v2; v3; v4] (4 x 128) ----------------
// v1=b3, v2=b2@W3, v3=(b1@W2)@W3, v4=((b0@W1)@W2)@W3

__global__ __launch_bounds__(128) void vvec_kernel(const float* __restrict__ b0, const float* __restrict__ b1,
                                                   const float* __restrict__ b2, const float* __restrict__ b3,
                                                   const float* __restrict__ W1, const float* __restrict__ W2,
                                                   const float* __restrict__ W3, float* __restrict__ vv) {
    __shared__ float ta[128], tb[128];
    int t = threadIdx.x;
    float s;
    vv[t] = b3[t];
    s = 0.f; for (int k = 0; k < 128; ++k) s += b2[k] * W3[k * 128 + t];
    vv[128 + t] = s;
    s = 0.f; for (int k = 0; k < 128; ++k) s += b1[k] * W2[k * 128 + t];
    ta[t] = s; __syncthreads();
    s = 0.f; for (int k = 0; k < 128; ++k) s += ta[k] * W3[k * 128 + t];
    vv[256 + t] = s;
    s = 0.f; for (int k = 0; k < 128; ++k) s += b0[k] * W1[k * 128 + t];
    tb[t] = s; __syncthreads();
    s = 0.f; for (int k = 0; k < 128; ++k) s += tb[k] * W2[k * 128 + t];
    __syncthreads();           // all reads of ta done before overwrite
    ta[t] = s; __syncthreads();
    s = 0.f; for (int k = 0; k < 128; ++k) s += ta[k] * W3[k * 128 + t];
    vv[384 + t] = s;
}

// ---------------- aggregation  x[i] = h[i] + sum_{j->i} h[j]  (feature-sliced) ----------------

__global__ __launch_bounds__(64) void agg_slice_kernel(const float* __restrict__ hin,
                                                       const int* __restrict__ offsets,
                                                       const int* __restrict__ srcsort,
                                                       float* __restrict__ x) {
    int bid  = blockIdx.x;
    int xcd  = bid & 7;
    int q    = bid >> 3;
    int slice = xcd >> 1;            // 0..3
    int node  = q * 2 + (xcd & 1);   // 0..19999
    int t    = threadIdx.x;          // 0..63
    int slot = t >> 3;               // 0..7
    int fl   = t & 7;
    int lo = offsets[node];
    int hi = offsets[node + 1];
    const float4* base = (const float4*)hin;   // row stride = 32 float4
    int soff = slice * 8 + fl;

    float4 a0 = make_float4(0.f, 0.f, 0.f, 0.f);
    float4 a1 = a0;

    int k = lo + slot;
    for (; k + 8 < hi; k += 16) {
        int s0 = srcsort[k];
        int s1 = srcsort[k + 8];
        float4 v0 = base[(size_t)s0 * 32 + soff];
        float4 v1 = base[(size_t)s1 * 32 + soff];
        a0.x += v0.x; a0.y += v0.y; a0.z += v0.z; a0.w += v0.w;
        a1.x += v1.x; a1.y += v1.y; a1.z += v1.z; a1.w += v1.w;
    }
    if (k < hi) {
        int s0 = srcsort[k];
        float4 v0 = base[(size_t)s0 * 32 + soff];
        a0.x += v0.x; a0.y += v0.y; a0.z += v0.z; a0.w += v0.w;
    }

    float4 acc;
    acc.x = a0.x + a1.x; acc.y = a0.y + a1.y;
    acc.z = a0.z + a1.z; acc.w = a0.w + a1.w;

    acc.x += __shfl_xor(acc.x, 8);  acc.y += __shfl_xor(acc.y, 8);
    acc.z += __shfl_xor(acc.z, 8);  acc.w += __shfl_xor(acc.w, 8);
    acc.x += __shfl_xor(acc.x, 16); acc.y += __shfl_xor(acc.y, 16);
    acc.z += __shfl_xor(acc.z, 16); acc.w += __shfl_xor(acc.w, 16);
    acc.x += __shfl_xor(acc.x, 32); acc.y += __shfl_xor(acc.y, 32);
    acc.z += __shfl_xor(acc.z, 32); acc.w += __shfl_xor(acc.w, 32);

    if (t < 8) {
        float4 sv = base[(size_t)node * 32 + soff];
        acc.x += sv.x; acc.y += sv.y; acc.z += sv.z; acc.w += sv.w;
        ((float4*)x)[(size_t)node * 32 + soff] = acc;
    }
}

// ---------------- GEMM: out = x @ W (+bias) (+rank-4 epilogue) ----------------
// Named scalars only in the inner loop (no runtime-indexable arrays -> no scratch).

__global__ __launch_bounds__(256) void gemm_kernel(const float* __restrict__ x,
                                                   const float* __restrict__ W,
                                                   const float* __restrict__ bias,
                                                   float* __restrict__ out, int rows,
                                                   const float* __restrict__ u2,
                                                   const float* __restrict__ u3,
                                                   const float* __restrict__ u4,
                                                   const float* __restrict__ vv) {
    __shared__ float Xs[TM][D];
    int t = threadIdx.x;
    int row0 = blockIdx.x * TM;
    int nrows = rows - row0; if (nrows > TM) nrows = TM;

    for (int i = t; i < nrows * (D / 4); i += 256) {
        int r  = i / (D / 4);
        int c4 = i % (D / 4);
        ((float4*)&Xs[r][0])[c4] = ((const float4*)&x[(size_t)(row0 + r) * D])[c4];
    }
    __syncthreads();

    int cg = t & 31;
    int rg = t >> 5;
    int j0 = cg * 4;
    int r0 = rg * 8;

    float acc[8][4];
    float4 bb = make_float4(0.f, 0.f, 0.f, 0.f);
    if (bias) bb = *((const float4*)&bias[j0]);
    #pragma unroll
    for (int i = 0; i < 8; ++i) {
        acc[i][0] = bb.x; acc[i][1] = bb.y; acc[i][2] = bb.z; acc[i][3] = bb.w;
    }

    for (int k4 = 0; k4 < D; k4 += 4) {
        float4 w0 = *((const float4*)&W[(k4 + 0) * D + j0]);
        float4 w1 = *((const float4*)&W[(k4 + 1) * D + j0]);
        float4 w2 = *((const float4*)&W[(k4 + 2) * D + j0]);
        float4 w3 = *((const float4*)&W[(k4 + 3) * D + j0]);
        #pragma unroll
        for (int i = 0; i < 8; ++i) {
            float4 xv = *((const float4*)&Xs[r0 + i][k4]);
            acc[i][0] += xv.x * w0.x; acc[i][0] += xv.y * w1.x;
            acc[i][0] += xv.z * w2.x; acc[i][0] += xv.w * w3.x;
            acc[i][1] += xv.x * w0.y; acc[i][1] += xv.y * w1.y;
            acc[i][1] += xv.z * w2.y; acc[i][1] += xv.w * w3.y;
            acc[i][2] += xv.x * w0.z; acc[i][2] += xv.y * w1.z;
            acc[i][2] += xv.z * w2.z; acc[i][2] += xv.w * w3.z;
            acc[i][3] += xv.x * w0.w; acc[i][3] += xv.y * w1.w;
            acc[i][3] += xv.z * w2.w; acc[i][3] += xv.w * w3.w;
        }
    }

    float4 v1 = make_float4(0.f,0.f,0.f,0.f), v2 = v1, v3 = v1, v4 = v1;
    if (vv) {
        v1 = *((const float4*)&vv[0   + j0]);
        v2 = *((const float4*)&vv[128 + j0]);
        v3 = *((const float4*)&vv[256 + j0]);
        v4 = *((const float4*)&vv[384 + j0]);
    }

    #pragma unroll
    for (int i = 0; i < 8; ++i) {
        int r = r0 + i;
        if (r < nrows) {
            float o0 = acc[i][0], o1 = acc[i][1], o2 = acc[i][2], o3 = acc[i][3];
            if (vv) {
                int ra = row0 + r;
                float a2 = u2[ra], a3 = u3[ra], a4 = u4[ra];
                o0 += a4 * v4.x + a3 * v3.x + a2 * v2.x + v1.x;
                o1 += a4 * v4.y + a3 * v3.y + a2 * v2.y + v1.y;
                o2 += a4 * v4.z + a3 * v3.z + a2 * v2.z + v1.z;
                o3 += a4 * v4.w + a3 * v3.w + a2 * v2.w + v1.w;
            }
            *((float4*)&out[(size_t)(row0 + r) * D + j0]) = make_float4(o0, o1, o2, o3);
        }
    }
}

// ---------------- launch ----------------

extern "C" void kernel_launch(void* const* d_in, const int* in_sizes, int n_in,
                              void* d_out, int out_size, void* d_ws, size_t ws_size,
                              hipStream_t stream) {
    const float* h   = (const float*)d_in[0];
    const int*   ei  = (const int*)d_in[1];
    const int*   src = ei;
    const int*   dst = ei + N_EDGES;
    const float* W0 = (const float*)d_in[2]; const float* b0 = (const float*)d_in[3];
    const float* W1 = (const float*)d_in[4]; const float* b1 = (const float*)d_in[5];
    const float* W2 = (const float*)d_in[6]; const float* b2 = (const float*)d_in[7];
    const float* W3 = (const float*)d_in[8]; const float* b3 = (const float*)d_in[9];
    float* out = (float*)d_out;

    char* ws = (char*)d_ws;
    auto alloc = [&](size_t bytes) {
        char* p = ws;
        ws += (bytes + 255) & ~(size_t)255;
        return p;
    };
    int*   counts  = (int*)alloc(N_NODES * sizeof(int));
    int*   offsets = (int*)alloc((N_NODES + 1) * sizeof(int));
    int*   cursor  = (int*)alloc(N_NODES * sizeof(int));
    int*   srcsort = (int*)alloc(N_EDGES * sizeof(int));
    float* bufA    = (float*)alloc((size_t)N_NODES * D * sizeof(float));
    float* bufB    = (float*)alloc((size_t)N_NODES * D * sizeof(float));
    float* P2      = (float*)alloc(D * D * sizeof(float));
    float* P3      = (float*)alloc(D * D * sizeof(float));
    float* WP      = (float*)alloc(D * D * sizeof(float));
    float* vv      = (float*)alloc(4 * D * sizeof(float));
    float* u2      = (float*)alloc(N_NODES * sizeof(float));
    float* u3      = (float*)alloc(N_NODES * sizeof(float));
    float* u4      = (float*)alloc(N_NODES * sizeof(float));

    // CSR
    zero_counts_kernel<<<(N_NODES + 255) / 256, 256, 0, stream>>>(counts);
    count_deg_kernel<<<(N_EDGES / 4 + 255) / 256, 256, 0, stream>>>((const int4*)dst, counts);
    scan_offsets_kernel<<<1, 1024, 0, stream>>>(counts, offsets, cursor);
    scatter_edges_kernel<<<(N_EDGES / 4 + 255) / 256, 256, 0, stream>>>(
        (const int4*)src, (const int4*)dst, cursor, srcsort);

    // weight chain: WP = W0 W1 W2 W3 (right-to-left)
    gemm_kernel<<<2, 256, 0, stream>>>(W2, W3, nullptr, P2, D, nullptr, nullptr, nullptr, nullptr);
    gemm_kernel<<<2, 256, 0, stream>>>(W1, P2, nullptr, P3, D, nullptr, nullptr, nullptr, nullptr);
    gemm_kernel<<<2, 256, 0, stream>>>(W0, P3, nullptr, WP, D, nullptr, nullptr, nullptr, nullptr);

    // bias chain vectors + degree chain
    vvec_kernel<<<1, 128, 0, stream>>>(b0, b1, b2, b3, W1, W2, W3, vv);
    deg_init_kernel<<<(N_NODES + 255) / 256, 256, 0, stream>>>(counts, u2);
    deg_spmv_kernel<<<(N_NODES + 255) / 256, 256, 0, stream>>>(offsets, srcsort, u2, u3);
    deg_spmv_kernel<<<(N_NODES + 255) / 256, 256, 0, stream>>>(offsets, srcsort, u3, u4);

    // g = (I+A)^4 h
    agg_slice_kernel<<<(N_NODES / 2) * 8, 64, 0, stream>>>(h,    offsets, srcsort, bufA);
    agg_slice_kernel<<<(N_NODES / 2) * 8, 64, 0, stream>>>(bufA, offsets, srcsort, bufB);
    agg_slice_kernel<<<(N_NODES / 2) * 8, 64, 0, stream>>>(bufB, offsets, srcsort, bufA);
    agg_slice_kernel<<<(N_NODES / 2) * 8, 64, 0, stream>>>(bufA, offsets, srcsort, bufB);

    // out = g @ WP + u4⊗v4 + u3⊗v3 + u2⊗v2 + 1⊗v1
    gemm_kernel<<<(N_NODES + TM - 1) / TM, 256, 0, stream>>>(
        bufB, WP, nullptr, out, N_NODES, u2, u3, u4, vv);
}